// Round 1
// baseline (874.004 us; speedup 1.0000x reference)
//
#include <hip/hip_runtime.h>
#include <hip/hip_bf16.h>

#define VERTS     100000
#define NCLUST    25000
#define BATCH_N   1024
#define ROWS_PER_BLOCK 16   // BATCH_N / gridDim.y

// out[b, v] = x[b, v2c[v]]
// Each thread: 4 vertices (int4 index load, float4 stores), 16 batch rows.
__global__ __launch_bounds__(256) void gather_pool_kernel(
    const float* __restrict__ x,     // [BATCH_N, NCLUST]
    const int*   __restrict__ v2c,   // [VERTS]
    float*       __restrict__ out)   // [BATCH_N, VERTS]
{
    const int v4 = blockIdx.x * blockDim.x + threadIdx.x;  // vertex-quad id
    if (v4 >= VERTS / 4) return;
    const int v = v4 * 4;

    // One vectorized index load, reused for 16 batch rows.
    const int4 idx = *reinterpret_cast<const int4*>(v2c + v);

    const int b0 = blockIdx.y * ROWS_PER_BLOCK;

#pragma unroll
    for (int i = 0; i < ROWS_PER_BLOCK; ++i) {
        const int b = b0 + i;
        const float* __restrict__ xrow = x + (size_t)b * NCLUST;
        float4 o;
        o.x = xrow[idx.x];
        o.y = xrow[idx.y];
        o.z = xrow[idx.z];
        o.w = xrow[idx.w];
        *reinterpret_cast<float4*>(out + (size_t)b * VERTS + v) = o;
    }
}

extern "C" void kernel_launch(void* const* d_in, const int* in_sizes, int n_in,
                              void* d_out, int out_size, void* d_ws, size_t ws_size,
                              hipStream_t stream) {
    const float* x   = (const float*)d_in[0];   // [1024, 25000] f32
    const int*   v2c = (const int*)d_in[1];     // [100000] i32
    float*       out = (float*)d_out;           // [1024, 100000] f32

    const int threads = 256;
    const int quads = VERTS / 4;                        // 25000
    dim3 grid((quads + threads - 1) / threads,          // 98
              BATCH_N / ROWS_PER_BLOCK);                // 64
    gather_pool_kernel<<<grid, dim3(threads), 0, stream>>>(x, v2c, out);
}

// Round 2
// 479.244 us; speedup vs baseline: 1.8237x; 1.8237x over previous
//
#include <hip/hip_runtime.h>

#define VERTS   100000
#define NCLUST  25000
#define BATCH_N 1024
#define THREADS 1024

typedef float  f32x4 __attribute__((ext_vector_type(4)));
typedef int    i32x4 __attribute__((ext_vector_type(4)));

// out[b, v] = x[b, v2c[v]]
// One block per batch row. Stage x[b,:] (100 KB) in LDS so every gather is a
// ds_read_b32 instead of a random L2/HBM access; x is read from HBM exactly
// once per row. v2c stays hot in L2 (400 KB, re-read by all 1024 blocks).
__global__ __launch_bounds__(THREADS) void gather_lds_kernel(
    const float* __restrict__ x,     // [BATCH_N, NCLUST]
    const int*   __restrict__ v2c,   // [VERTS]
    float*       __restrict__ out)   // [BATCH_N, VERTS]
{
    extern __shared__ float lds[];   // NCLUST floats = 100000 bytes
    const int b   = blockIdx.x;
    const int tid = threadIdx.x;

    // Phase 1: coalesced float4 staging of the whole row into LDS.
    // Non-temporal: each row is touched exactly once — don't pollute L2/L3.
    const f32x4* __restrict__ xrow4 =
        reinterpret_cast<const f32x4*>(x + (size_t)b * NCLUST);
    f32x4* lds4 = reinterpret_cast<f32x4*>(lds);
    for (int i = tid; i < NCLUST / 4; i += THREADS) {
        lds4[i] = __builtin_nontemporal_load(&xrow4[i]);
    }
    __syncthreads();

    // Phase 2: int4 index load (L2-hit), 4 LDS gathers, float4 streaming store.
    const i32x4* __restrict__ v2c4 = reinterpret_cast<const i32x4*>(v2c);
    f32x4* __restrict__ out4 =
        reinterpret_cast<f32x4*>(out + (size_t)b * VERTS);
    for (int q = tid; q < VERTS / 4; q += THREADS) {
        const i32x4 idx = v2c4[q];
        f32x4 o;
        o.x = lds[idx.x];
        o.y = lds[idx.y];
        o.z = lds[idx.z];
        o.w = lds[idx.w];
        __builtin_nontemporal_store(o, &out4[q]);
    }
}

extern "C" void kernel_launch(void* const* d_in, const int* in_sizes, int n_in,
                              void* d_out, int out_size, void* d_ws, size_t ws_size,
                              hipStream_t stream) {
    const float* x   = (const float*)d_in[0];   // [1024, 25000] f32
    const int*   v2c = (const int*)d_in[1];     // [100000] i32
    float*       out = (float*)d_out;           // [1024, 100000] f32

    const int lds_bytes = NCLUST * (int)sizeof(float);  // 100000 B > 64 KB default cap
    static bool attr_set = false;  // idempotent host-side attribute, not a stream op
    if (!attr_set) {
        hipFuncSetAttribute(reinterpret_cast<const void*>(gather_lds_kernel),
                            hipFuncAttributeMaxDynamicSharedMemorySize, lds_bytes);
        attr_set = true;
    }

    gather_lds_kernel<<<BATCH_N, THREADS, lds_bytes, stream>>>(x, v2c, out);
}